// Round 6
// baseline (350.078 us; speedup 1.0000x reference)
//
#include <hip/hip_runtime.h>

#define T_STEPS 100
#define CHUNKS  25    // 100 floats = 25 float4 per element
#define TPB     64    // one wave per block
#define ELEMS   64    // elements per tile (== TPB)
#define GRID    2048  // 8 blocks/CU x 256 CU, all co-resident; 8192/2048 = 4 tiles/block
// LDS: 2 x (64 elems * 25 dwords) * 4B = 12.8 KB -> 8 blocks/CU = 102.4/160 KB

// Persistent grid-stride blocks: no block respawns, stores of tile t stay in
// flight across tile t+1's load+compute.
//
// R5 POST-MORTEM baked in: cross-lane LDS transpose WITHOUT a sync primitive
// is a data race the compiler may (and did) reorder -> absmax 255 (garbage
// LDS). Fix: __syncthreads() between pack-writes and transpose-reads. It's
// cheap here: when it executes, the 25 loads are consumed and the previous
// tile's stores are ~2500 cyc old, so the forced vmcnt(0) is near-drained.
// WAR across tiles (writes t+1 vs reads t) is removed by DOUBLE-BUFFERING the
// spike LDS instead of a second barrier -> no store drain at loop bottom.
//
//   loads:   25 strided float4/lane -> registers (R1/R4-proven clean read path)
//   compute: register recurrence; 4 spikes packed per dword -> LDS own row
//            (dword addr lane*25+c: 25 odd -> uniform 2/bank = free)
//   stage-out: sp[k*64+lane] stride-1 dwords (free), v_cvt_f32_ubyte0..3,
//            coalesced full-line float4 stores (WRITE_SIZE stays ideal)
//
// NUMERICS: bit-identical to numpy reference (verified R1-R4, absmax 0):
//   fp contract OFF; op order ((mem*TAU)+x)-w ; (BETA*w)+(1-BETA)*((A*m)+(B*s));
//   mem - spike*THRESH ; BETA->0.9f, (1-BETA)->0.1f ; *0.5f exact (exp shift).
//   Byte {0,1} -> float conversion is exact.
__global__ __launch_bounds__(TPB) void lif_kernel(const float* __restrict__ x,
                                                  float* __restrict__ out,
                                                  int ntiles) {
#pragma clang fp contract(off)
    __shared__ unsigned int sp[2][ELEMS * CHUNKS];  // double-buffered spike packs

    const int lane = threadIdx.x;
    int parity = 0;

    for (int t = blockIdx.x; t < ntiles; t += GRID, parity ^= 1) {
        unsigned int* buf = sp[parity];
        const size_t tile4 = (size_t)t * (ELEMS * CHUNKS);
        const float4* __restrict__ xp = (const float4*)x + tile4 + (size_t)lane * CHUNKS;
        float4* __restrict__ ob = (float4*)out + tile4;

        // ---- load: own element's 25 float4 chunks straight to registers ----
        float4 xs[CHUNKS];
#pragma unroll
        for (int c = 0; c < CHUNKS; ++c) xs[c] = xp[c];

        // ---- compute: register recurrence, spikes packed 4/dword to LDS ----
        float mem = 0.0f;
        float w = 0.0f;
#pragma unroll
        for (int c = 0; c < CHUNKS; ++c) {
            float xv[4] = {xs[c].x, xs[c].y, xs[c].z, xs[c].w};
            unsigned int pack = 0;
#pragma unroll
            for (int j = 0; j < 4; ++j) {
                mem = (mem * 0.5f + xv[j]) - w;                    // ((mem*TAU)+x)-w
                bool b = (mem - 0.5f) > 0.0f;                      // ZIF forward
                float spike = b ? 1.0f : 0.0f;
                w = 0.9f * w + 0.1f * (0.5f * mem + 0.5f * spike); // numpy order
                mem = mem - spike * 0.5f;                          // soft reset
                pack |= b ? (1u << (8 * j)) : 0u;
            }
            buf[lane * CHUNKS + c] = pack;
        }

        __syncthreads();  // REQUIRED: compiler-visible fence for the cross-lane
                          // transpose (R5 raced without it). vmcnt near-drained
                          // here: loads consumed, prev stores ~2500 cyc old.

        // ---- stage-out: stride-1 LDS dwords -> 4x cvt -> coalesced stores --
#pragma unroll
        for (int k = 0; k < CHUNKS; ++k) {
            unsigned int p = buf[k * TPB + lane];
            float4 s;
            s.x = (float)(p & 0xffu);          // v_cvt_f32_ubyte0
            s.y = (float)((p >> 8) & 0xffu);   // v_cvt_f32_ubyte1
            s.z = (float)((p >> 16) & 0xffu);  // v_cvt_f32_ubyte2
            s.w = (float)(p >> 24);            // v_cvt_f32_ubyte3
            ob[k * TPB + lane] = s;
        }
        // no trailing barrier: next tile writes the OTHER buffer (no WAR), and
        // reads of this buffer can't be passed by its t+2 writes across the
        // interleaving __syncthreads() fences.
    }
}

extern "C" void kernel_launch(void* const* d_in, const int* in_sizes, int n_in,
                              void* d_out, int out_size, void* d_ws, size_t ws_size,
                              hipStream_t stream) {
    const float* x = (const float*)d_in[0];
    float* out = (float*)d_out;
    int n_elem = in_sizes[0] / T_STEPS;       // 64*8192 = 524288
    int ntiles = n_elem / ELEMS;              // 8192 tiles, 4 per block

    lif_kernel<<<GRID, TPB, 0, stream>>>(x, out, ntiles);
}